// Round 8
// baseline (128.762 us; speedup 1.0000x reference)
//
#include <hip/hip_runtime.h>
#include <hip/hip_bf16.h>

#define K_DIM 16384
#define M_DIM 512
#define N_DIM 2560
#define BM 256
#define BN 160
#define BK 64
#define KSPLIT 8
#define KCH (K_DIM / KSPLIT)   // 2048
#define NT (KCH / BK)          // 32 K-steps per block

typedef float f32x4 __attribute__((ext_vector_type(4)));
typedef __bf16 bf16x8 __attribute__((ext_vector_type(8)));

__device__ __forceinline__ unsigned short f2bf(float f){
  union { float f; unsigned u; } v; v.f = f;
  unsigned r = v.u + 0x7FFFu + ((v.u >> 16) & 1u);
  return (unsigned short)(r >> 16);
}
__device__ __forceinline__ unsigned bfpack2(float lo, float hi){
  return (unsigned)f2bf(lo) | ((unsigned)f2bf(hi) << 16);
}

// K1: w_mean[c] = mean_f conv1_w[f][c]; b_mean = mean(conv1_b)
__global__ __launch_bounds__(256)
void prep_kernel(const float* __restrict__ conv1_w, const float* __restrict__ conv1_b,
                 float* __restrict__ w_mean, float* __restrict__ b_mean)
{
  int c = blockIdx.x * 256 + threadIdx.x;
  if (c < K_DIM){
    float s = 0.f;
    #pragma unroll
    for (int f = 0; f < 10; ++f) s += conv1_w[f * K_DIM + c];
    w_mean[c] = s * 0.1f;
  }
  if (blockIdx.x == 0 && threadIdx.x == 0){
    float s = 0.f;
    #pragma unroll
    for (int f = 0; f < 10; ++f) s += conv1_b[f];
    *b_mean = s * 0.1f;
  }
}

// K2: pooled[row] = x[row,:].w_mean + b_mean  AND  xbf[row,:] = bf16(x[row,:])
__global__ __launch_bounds__(256)
void pooled_kernel(const float* __restrict__ X, const float* __restrict__ w_mean,
                   const float* __restrict__ b_mean, float* __restrict__ pooled,
                   unsigned short* __restrict__ xbf)
{
  const int row = blockIdx.x;
  const int tid = threadIdx.x;
  const float* xr = X + (size_t)row * K_DIM;
  unsigned short* xb = xbf + (size_t)row * K_DIM;
  float s = 0.f;
  #pragma unroll 2
  for (int i = 0; i < 8; ++i){
    int idx = (tid + 256 * i) * 8;
    float4 a0 = *(const float4*)(xr + idx);
    float4 a1 = *(const float4*)(xr + idx + 4);
    float4 w0 = *(const float4*)(w_mean + idx);
    float4 w1 = *(const float4*)(w_mean + idx + 4);
    s += a0.x*w0.x + a0.y*w0.y + a0.z*w0.z + a0.w*w0.w
       + a1.x*w1.x + a1.y*w1.y + a1.z*w1.z + a1.w*w1.w;
    uint4 p;
    p.x = bfpack2(a0.x, a0.y); p.y = bfpack2(a0.z, a0.w);
    p.z = bfpack2(a1.x, a1.y); p.w = bfpack2(a1.z, a1.w);
    *(uint4*)(xb + idx) = p;
  }
  #pragma unroll
  for (int off = 32; off; off >>= 1) s += __shfl_down(s, off);
  __shared__ float red[4];
  if ((tid & 63) == 0) red[tid >> 6] = s;
  __syncthreads();
  if (tid == 0) pooled[row] = red[0] + red[1] + red[2] + red[3] + *b_mean;
}

// K3: gates
__global__ __launch_bounds__(512)
void gates_kernel(const float* __restrict__ pooled, const float* __restrict__ fw,
                  const float* __restrict__ fb, const float* __restrict__ aw,
                  float* __restrict__ gates)
{
  __shared__ float ps[512];
  int tid = threadIdx.x;
  ps[tid] = pooled[tid];
  __syncthreads();
  int b = tid >> 5, s = tid & 31;
  float z = fb[s];
  #pragma unroll
  for (int t = 0; t < 32; ++t) z += ps[b * 32 + t] * fw[s * 32 + t];
  float mx = z;
  #pragma unroll
  for (int off = 16; off; off >>= 1) mx = fmaxf(mx, __shfl_xor(mx, off));
  float e = expf(z - mx);
  float sum = e;
  #pragma unroll
  for (int off = 16; off; off >>= 1) sum += __shfl_xor(sum, off);
  float sm = e / sum;
  float relu = z > 0.f ? z : 0.f;
  float sig = 1.f / (1.f + expf(-z));
  gates[tid] = aw[0] * relu + aw[1] * sig + aw[2] * sm;
}

// K4: BM=256 x BN=160, BK=64, KSPLIT=8 -> grid 256 (1 block/CU). 8 waves 4m x 2n,
// wave tile 64x80 (acc[4][5]). kz=id&7 XCD-pinned. m201-style per-phase schedule:
//   per K-step: [issue B-loads(t+2); issue A-gll(t+2)] then 2 phases
//   {ds_read 9xb128; s_barrier; lgkmcnt(0); setprio(1); 20 MFMA; setprio(0); s_barrier}
//   then vmcnt(4) (drains gll(t+1)+B(t+2), keeps gll(t+2) in flight) + cvt+ds_write B.
// A triple-buffered (gll lands with one full K-step of slack); B LDS double-buffered.
__global__ __launch_bounds__(512, 2)
void gemm_kernel(const unsigned short* __restrict__ Abf, const float* __restrict__ W,
                 float* __restrict__ outp, int mode)
{
  __shared__ __align__(16) char smem[3 * 32768 + 2 * 20480];  // A 96KB + B 40KB

  const int tid  = threadIdx.x;
  const int lane = tid & 63;
  const int wv   = tid >> 6;
  const int wm   = (wv >> 1) * 64;      // 4 m-waves
  const int wn   = (wv & 1) * 80;       // 2 n-waves

  const int id = blockIdx.x;
  const int kz = id & 7;
  const int r  = id >> 3;               // 0..31
  const int m0 = (r & 1) * BM;
  const int n0 = (r >> 1) * BN;
  const int kbase = kz * KCH;

  f32x4 acc[4][5] = {};

  // A gll mapping: chunk u = j*512 + tid -> row = j*64 + (tid>>3), c8 = tid&7.
  // LDS[row][c8] holds A[row][c8 ^ (row&7)]; row&7 == (tid>>3)&7.
  const int arow0 = tid >> 3;
  const int ac8   = (tid & 7) ^ (arow0 & 7);
  const unsigned short* asrc = Abf + (size_t)(m0 + arow0) * K_DIM + ac8 * 8;
  const int adst = tid * 16;

  auto stageA = [&](int buf, int k0){
    char* dst = smem + buf * 32768;
    #pragma unroll
    for (int j = 0; j < 4; ++j){
      __builtin_amdgcn_global_load_lds(
        (const __attribute__((address_space(1))) void*)(asrc + (size_t)j * 64 * K_DIM + k0),
        (__attribute__((address_space(3))) void*)(dst + j * 8192 + adst),
        16, 0, 0);
    }
  };

  // B staging: threads 0..319 (waves 0-4): row = tid>>1, half = tid&1 -> 32 fp32.
  const int brow  = tid >> 1;
  const int bhalf = tid & 1;
  const bool bact = (tid < 320);
  const float* bsrc = W + (size_t)(n0 + (bact ? brow : 0)) * K_DIM + kbase + bhalf * 32;
  int boff[4];
  #pragma unroll
  for (int h = 0; h < 4; ++h)
    boff[h] = brow * 128 + ((((bhalf * 4 + h) * 16)) ^ ((brow & 7) << 4));

  float4 rb[8];
  auto loadB = [&](int kt){
    if (bact){
      const float* p = bsrc + kt * BK;
      #pragma unroll
      for (int q = 0; q < 8; ++q) rb[q] = *(const float4*)(p + q * 4);
    }
  };
  auto writeB = [&](int buf){
    if (bact){
      char* dst = smem + 98304 + buf * 20480;
      #pragma unroll
      for (int h = 0; h < 4; ++h){
        uint4 u;
        u.x = bfpack2(rb[2*h].x,   rb[2*h].y);   u.y = bfpack2(rb[2*h].z,   rb[2*h].w);
        u.z = bfpack2(rb[2*h+1].x, rb[2*h+1].y); u.w = bfpack2(rb[2*h+1].z, rb[2*h+1].w);
        *(uint4*)(dst + boff[h]) = u;
      }
    }
  };

  // one phase = {ds_read cluster; barrier; lgkmcnt(0); setprio; 20 MFMA; setprio; barrier}
  auto phase = [&](const char* A_, const char* B_, int kk){
    bf16x8 af[4], bfv[5];
    const int kbyte = kk * 64 + (lane >> 4) * 16;
    #pragma unroll
    for (int i = 0; i < 4; ++i){
      int row = wm + i * 16 + (lane & 15);
      af[i] = *(const bf16x8*)(A_ + row * 128 + (kbyte ^ ((row & 7) << 4)));
    }
    #pragma unroll
    for (int j = 0; j < 5; ++j){
      int row = wn + j * 16 + (lane & 15);
      bfv[j] = *(const bf16x8*)(B_ + row * 128 + (kbyte ^ ((row & 7) << 4)));
    }
    __builtin_amdgcn_s_barrier();
    asm volatile("s_waitcnt lgkmcnt(0)" ::: "memory");
    __builtin_amdgcn_sched_barrier(0);
    __builtin_amdgcn_s_setprio(1);
    #pragma unroll
    for (int i = 0; i < 4; ++i)
      #pragma unroll
      for (int j = 0; j < 5; ++j)
        acc[i][j] = __builtin_amdgcn_mfma_f32_16x16x32_bf16(af[i], bfv[j], acc[i][j], 0, 0, 0);
    __builtin_amdgcn_s_setprio(0);
    __builtin_amdgcn_sched_barrier(0);
    __builtin_amdgcn_s_barrier();
  };

  // ---- prologue ----
  loadB(0); stageA(0, kbase);                    // outstanding: B0(8)+A0(4)  [w5-7: A0(4)]
  asm volatile("s_waitcnt vmcnt(4)" ::: "memory");   // drain B0 (A0 may fly)
  writeB(0);
  loadB(1); stageA(1, kbase + BK);               // + B1(8)+A1(4)
  asm volatile("s_waitcnt vmcnt(4)" ::: "memory");   // drain A0,B1; keep A1
  writeB(1);
  asm volatile("s_waitcnt lgkmcnt(0)" ::: "memory");
  __builtin_amdgcn_s_barrier();                  // tile0 (A0,B0) published; A1 in flight

  // ---- main loop ----
  for (int t = 0; t < NT; ++t){
    const char* Ab = smem + (t % 3) * 32768;
    const char* Bb = smem + 98304 + (t & 1) * 20480;
    if (t + 2 < NT){
      loadB(t + 2);                 // 8 vmem -> rb
      stageA((t + 2) % 3, kbase + (t + 2) * BK);   // 4 gll
    }
    phase(Ab, Bb, 0);
    phase(Ab, Bb, 1);
    if (t + 2 < NT){
      // outstanding: gll(t+1)=4, B(t+2)=8, gll(t+2)=4  -> keep newest 4
      asm volatile("s_waitcnt vmcnt(4)" ::: "memory");
      __builtin_amdgcn_sched_barrier(0);
      writeB(t & 1);                // bufB[(t+2)&1] == bufB[t&1]; readers drained
    } else if (t == NT - 2){
      asm volatile("s_waitcnt vmcnt(0)" ::: "memory");   // drain gll(NT-1)
      __builtin_amdgcn_sched_barrier(0);
    }
  }

  // ---- epilogue ----
  if (mode == 0){
    float* P = outp + (size_t)kz * M_DIM * N_DIM;
    #pragma unroll
    for (int i = 0; i < 4; ++i){
      int rbase = m0 + wm + i * 16 + (lane >> 4) * 4;
      #pragma unroll
      for (int j = 0; j < 5; ++j){
        int col = n0 + wn + j * 16 + (lane & 15);
        #pragma unroll
        for (int r2 = 0; r2 < 4; ++r2)
          P[(size_t)(rbase + r2) * N_DIM + col] = acc[i][j][r2];
      }
    }
  } else {
    #pragma unroll
    for (int i = 0; i < 4; ++i){
      int rbase = m0 + wm + i * 16 + (lane >> 4) * 4;
      #pragma unroll
      for (int j = 0; j < 5; ++j){
        int col = n0 + wn + j * 16 + (lane & 15);
        #pragma unroll
        for (int r2 = 0; r2 < 4; ++r2)
          atomicAdd(&outp[(size_t)(rbase + r2) * N_DIM + col], acc[i][j][r2]);
      }
    }
  }
}

// K5a: out[m,n] = gates[m] * (sum_z partial[z,m,n] + bias[n])
__global__ __launch_bounds__(256)
void reduce_kernel(const float* __restrict__ part, const float* __restrict__ gates,
                   const float* __restrict__ bias, float* __restrict__ out, int ksplit)
{
  int i4 = blockIdx.x * 256 + threadIdx.x;
  if (i4 >= M_DIM * N_DIM / 4) return;
  size_t off = (size_t)i4 * 4;
  int m = (int)(off / N_DIM);
  int n = (int)(off % N_DIM);
  float sx = 0.f, sy = 0.f, sz = 0.f, sw = 0.f;
  for (int z = 0; z < ksplit; ++z){
    float4 p = *(const float4*)(part + (size_t)z * M_DIM * N_DIM + off);
    sx += p.x; sy += p.y; sz += p.z; sw += p.w;
  }
  float4 bv = *(const float4*)(bias + n);
  float g = gates[m];
  float4 o;
  o.x = g * (sx + bv.x); o.y = g * (sy + bv.y);
  o.z = g * (sz + bv.z); o.w = g * (sw + bv.w);
  *(float4*)(out + off) = o;
}

// K5b: finalize after atomic accumulation
__global__ __launch_bounds__(256)
void finalize_kernel(float* __restrict__ out, const float* __restrict__ gates,
                     const float* __restrict__ bias)
{
  int i4 = blockIdx.x * 256 + threadIdx.x;
  if (i4 >= M_DIM * N_DIM / 4) return;
  size_t off = (size_t)i4 * 4;
  int m = (int)(off / N_DIM);
  int n = (int)(off % N_DIM);
  float4 o = *(const float4*)(out + off);
  float4 bv = *(const float4*)(bias + n);
  float g = gates[m];
  o.x = g * (o.x + bv.x); o.y = g * (o.y + bv.y);
  o.z = g * (o.z + bv.z); o.w = g * (o.w + bv.w);
  *(float4*)(out + off) = o;
}

extern "C" void kernel_launch(void* const* d_in, const int* in_sizes, int n_in,
                              void* d_out, int out_size, void* d_ws, size_t ws_size,
                              hipStream_t stream)
{
  const float* input   = (const float*)d_in[0];
  const float* aw      = (const float*)d_in[2];
  const float* conv1_w = (const float*)d_in[3];
  const float* conv1_b = (const float*)d_in[4];
  const float* G3_w    = (const float*)d_in[5];
  const float* G3_b    = (const float*)d_in[6];
  const float* ffnn1_w = (const float*)d_in[7];
  const float* ffnn1_b = (const float*)d_in[8];
  float* out = (float*)d_out;

  float* wsf    = (float*)d_ws;
  float* w_mean = wsf;               // 16384 f
  float* pooled = wsf + 16384;       // 512 f
  float* gates  = wsf + 16896;       // 512 f
  float* b_mean = wsf + 17408;       // 64 f pad
  unsigned short* xbf = (unsigned short*)(wsf + 17472);        // 512*16384 bf16 = 16MB
  float* partial = wsf + 17472 + (size_t)M_DIM * K_DIM / 2;    // 8 * 512*2560 f

  const size_t need_det = ((size_t)17472 + (size_t)M_DIM * K_DIM / 2
                           + (size_t)KSPLIT * M_DIM * N_DIM) * 4;   // ~58.8MB

  prep_kernel<<<64, 256, 0, stream>>>(conv1_w, conv1_b, w_mean, b_mean);
  pooled_kernel<<<512, 256, 0, stream>>>(input, w_mean, b_mean, pooled, xbf);
  gates_kernel<<<1, 512, 0, stream>>>(pooled, ffnn1_w, ffnn1_b, aw, gates);

  const int n4 = M_DIM * N_DIM / 4;
  const int grid = (M_DIM / BM) * (N_DIM / BN) * KSPLIT;   // 2*16*8 = 256
  if (ws_size >= need_det){
    gemm_kernel<<<grid, 512, 0, stream>>>(xbf, G3_w, partial, 0);
    reduce_kernel<<<(n4 + 255) / 256, 256, 0, stream>>>(partial, gates, G3_b, out, KSPLIT);
  } else {
    hipMemsetAsync(d_out, 0, (size_t)out_size * sizeof(float), stream);
    gemm_kernel<<<grid, 512, 0, stream>>>(xbf, G3_w, out, 2);
    finalize_kernel<<<(n4 + 255) / 256, 256, 0, stream>>>(out, gates, G3_b);
  }
}

// Round 9
// 114.229 us; speedup vs baseline: 1.1272x; 1.1272x over previous
//
#include <hip/hip_runtime.h>
#include <hip/hip_bf16.h>

#define K_DIM 16384
#define M_DIM 512
#define N_DIM 2560
#define BM 128
#define BN 160
#define BK 64
#define KSPLIT 8
#define KCH (K_DIM / KSPLIT)   // 2048
#define NT (KCH / BK)          // 32

typedef float f32x4 __attribute__((ext_vector_type(4)));
typedef __bf16 bf16x8 __attribute__((ext_vector_type(8)));

__device__ __forceinline__ unsigned short f2bf(float f){
  union { float f; unsigned u; } v; v.f = f;
  unsigned r = v.u + 0x7FFFu + ((v.u >> 16) & 1u);
  return (unsigned short)(r >> 16);
}
__device__ __forceinline__ unsigned bfpack2(float lo, float hi){
  return (unsigned)f2bf(lo) | ((unsigned)f2bf(hi) << 16);
}

// K1: w_mean[c] = mean_f conv1_w[f][c]; b_mean = mean(conv1_b)
__global__ __launch_bounds__(256)
void prep_kernel(const float* __restrict__ conv1_w, const float* __restrict__ conv1_b,
                 float* __restrict__ w_mean, float* __restrict__ b_mean)
{
  int c = blockIdx.x * 256 + threadIdx.x;
  if (c < K_DIM){
    float s = 0.f;
    #pragma unroll
    for (int f = 0; f < 10; ++f) s += conv1_w[f * K_DIM + c];
    w_mean[c] = s * 0.1f;
  }
  if (blockIdx.x == 0 && threadIdx.x == 0){
    float s = 0.f;
    #pragma unroll
    for (int f = 0; f < 10; ++f) s += conv1_b[f];
    *b_mean = s * 0.1f;
  }
}

// K2: pooled[row] = x[row,:].w_mean + b_mean  AND  xbf[row,:] = bf16(x[row,:])
__global__ __launch_bounds__(256)
void pooled_kernel(const float* __restrict__ X, const float* __restrict__ w_mean,
                   const float* __restrict__ b_mean, float* __restrict__ pooled,
                   unsigned short* __restrict__ xbf)
{
  const int row = blockIdx.x;
  const int tid = threadIdx.x;
  const float* xr = X + (size_t)row * K_DIM;
  unsigned short* xb = xbf + (size_t)row * K_DIM;
  float s = 0.f;
  #pragma unroll 2
  for (int i = 0; i < 8; ++i){
    int idx = (tid + 256 * i) * 8;
    float4 a0 = *(const float4*)(xr + idx);
    float4 a1 = *(const float4*)(xr + idx + 4);
    float4 w0 = *(const float4*)(w_mean + idx);
    float4 w1 = *(const float4*)(w_mean + idx + 4);
    s += a0.x*w0.x + a0.y*w0.y + a0.z*w0.z + a0.w*w0.w
       + a1.x*w1.x + a1.y*w1.y + a1.z*w1.z + a1.w*w1.w;
    uint4 p;
    p.x = bfpack2(a0.x, a0.y); p.y = bfpack2(a0.z, a0.w);
    p.z = bfpack2(a1.x, a1.y); p.w = bfpack2(a1.z, a1.w);
    *(uint4*)(xb + idx) = p;
  }
  #pragma unroll
  for (int off = 32; off; off >>= 1) s += __shfl_down(s, off);
  __shared__ float red[4];
  if ((tid & 63) == 0) red[tid >> 6] = s;
  __syncthreads();
  if (tid == 0) pooled[row] = red[0] + red[1] + red[2] + red[3] + *b_mean;
}

// K3: gates
__global__ __launch_bounds__(512)
void gates_kernel(const float* __restrict__ pooled, const float* __restrict__ fw,
                  const float* __restrict__ fb, const float* __restrict__ aw,
                  float* __restrict__ gates)
{
  __shared__ float ps[512];
  int tid = threadIdx.x;
  ps[tid] = pooled[tid];
  __syncthreads();
  int b = tid >> 5, s = tid & 31;
  float z = fb[s];
  #pragma unroll
  for (int t = 0; t < 32; ++t) z += ps[b * 32 + t] * fw[s * 32 + t];
  float mx = z;
  #pragma unroll
  for (int off = 16; off; off >>= 1) mx = fmaxf(mx, __shfl_xor(mx, off));
  float e = expf(z - mx);
  float sum = e;
  #pragma unroll
  for (int off = 16; off; off >>= 1) sum += __shfl_xor(sum, off);
  float sm = e / sum;
  float relu = z > 0.f ? z : 0.f;
  float sig = 1.f / (1.f + expf(-z));
  gates[tid] = aw[0] * relu + aw[1] * sig + aw[2] * sm;
}

// K4: m97-style small-block GEMM for CO-RESIDENCY. BM=128 x BN=160, BK=64,
// 4 waves (256 thr), wave tile 64x80 (acc[4][5]). LDS 36KB single-buffered,
// plain 2-barrier full-drain loop (__syncthreads only) -- per-block drain stalls
// are hidden by the 2-3 OTHER resident blocks per CU (m114/m97 overlap).
// Grid 4*16*8 = 512 (2/CU resident min, 3 if VGPR<=170). kz=id&7 XCD-pinned,
// m-fastest (4 m-blocks sharing a W-strip -> same XCD, W read once from L3).
// A: global_load_lds w/ pre-swizzled source. B: fp32 reg-stage, cvt->bf16, LDS.
__global__ __launch_bounds__(256, 3)
void gemm_kernel(const unsigned short* __restrict__ Abf, const float* __restrict__ W,
                 float* __restrict__ outp, int mode)
{
  __shared__ __align__(16) char smem[36864];   // A [128][128B] 16KB + B [160][128B] 20KB
  char* As = smem;
  char* Bs = smem + 16384;

  const int tid  = threadIdx.x;
  const int lane = tid & 63;
  const int wv   = tid >> 6;          // 0..3
  const int wm   = (wv >> 1) * 64;    // 2 m-waves
  const int wn   = (wv & 1) * 80;     // 2 n-waves

  const int id = blockIdx.x;
  const int kz = id & 7;
  const int r  = id >> 3;             // 0..63
  const int m0 = (r & 3) * BM;
  const int n0 = (r >> 2) * BN;
  const int kbase = kz * KCH;

  f32x4 acc[4][5] = {};

  // A gll: chunk u = j*256+tid -> row = j*32 + (tid>>3), c8 = tid&7 (pre-swizzled src)
  const int arow0 = tid >> 3;                     // 0..31
  const int ac8   = (tid & 7) ^ (arow0 & 7);
  const unsigned short* asrc = Abf + (size_t)(m0 + arow0) * K_DIM + ac8 * 8;
  const int adst = tid * 16;

  // B: chunk u = j*256+tid (j=0..9) -> row = j*16 + (tid>>4), c4 = tid&15 (float4)
  const int btrow = tid >> 4;                     // 0..15
  const int bc4   = tid & 15;
  const float* bsrc0 = W + (size_t)(n0 + btrow) * K_DIM + bc4 * 4;
  const int boff = btrow * 128 + (((bc4 >> 1) ^ (btrow & 7)) << 4) + (bc4 & 1) * 8;

  for (int t = 0; t < NT; ++t){
    const int koff = kbase + t * BK;
    // B fp32 loads (10 x float4)
    float4 rb[10];
    #pragma unroll
    for (int j = 0; j < 10; ++j)
      rb[j] = *(const float4*)(bsrc0 + (size_t)j * 16 * K_DIM + koff);
    // A global->LDS (4 x 16B per thread)
    #pragma unroll
    for (int j = 0; j < 4; ++j){
      __builtin_amdgcn_global_load_lds(
        (const __attribute__((address_space(1))) void*)(asrc + (size_t)j * 32 * K_DIM + koff),
        (__attribute__((address_space(3))) void*)(As + j * 4096 + adst),
        16, 0, 0);
    }
    // B cvt -> LDS (10 x 8B, swizzled)
    #pragma unroll
    for (int j = 0; j < 10; ++j){
      uint2 u;
      u.x = bfpack2(rb[j].x, rb[j].y);
      u.y = bfpack2(rb[j].z, rb[j].w);
      *(uint2*)(Bs + j * 2048 + boff) = u;
    }
    __syncthreads();          // drains vmcnt(0)+lgkmcnt(0): A & B tile ready

    #pragma unroll
    for (int kk = 0; kk < 2; ++kk){
      bf16x8 af[4], bfv[5];
      const int kbyte = kk * 64 + (lane >> 4) * 16;
      #pragma unroll
      for (int i = 0; i < 4; ++i){
        int row = wm + i * 16 + (lane & 15);
        af[i] = *(const bf16x8*)(As + row * 128 + (kbyte ^ ((row & 7) << 4)));
      }
      #pragma unroll
      for (int j = 0; j < 5; ++j){
        int row = wn + j * 16 + (lane & 15);
        bfv[j] = *(const bf16x8*)(Bs + row * 128 + (kbyte ^ ((row & 7) << 4)));
      }
      #pragma unroll
      for (int i = 0; i < 4; ++i)
        #pragma unroll
        for (int j = 0; j < 5; ++j)
          acc[i][j] = __builtin_amdgcn_mfma_f32_16x16x32_bf16(af[i], bfv[j], acc[i][j], 0, 0, 0);
    }
    __syncthreads();          // safe to overwrite tile next iter
  }

  if (mode == 0){
    float* P = outp + (size_t)kz * M_DIM * N_DIM;
    #pragma unroll
    for (int i = 0; i < 4; ++i){
      int rbase = m0 + wm + i * 16 + (lane >> 4) * 4;
      #pragma unroll
      for (int j = 0; j < 5; ++j){
        int col = n0 + wn + j * 16 + (lane & 15);
        #pragma unroll
        for (int r2 = 0; r2 < 4; ++r2)
          P[(size_t)(rbase + r2) * N_DIM + col] = acc[i][j][r2];
      }
    }
  } else {
    #pragma unroll
    for (int i = 0; i < 4; ++i){
      int rbase = m0 + wm + i * 16 + (lane >> 4) * 4;
      #pragma unroll
      for (int j = 0; j < 5; ++j){
        int col = n0 + wn + j * 16 + (lane & 15);
        #pragma unroll
        for (int r2 = 0; r2 < 4; ++r2)
          atomicAdd(&outp[(size_t)(rbase + r2) * N_DIM + col], acc[i][j][r2]);
      }
    }
  }
}

// K5a: out[m,n] = gates[m] * (sum_z partial[z,m,n] + bias[n])
__global__ __launch_bounds__(256)
void reduce_kernel(const float* __restrict__ part, const float* __restrict__ gates,
                   const float* __restrict__ bias, float* __restrict__ out, int ksplit)
{
  int i4 = blockIdx.x * 256 + threadIdx.x;
  if (i4 >= M_DIM * N_DIM / 4) return;
  size_t off = (size_t)i4 * 4;
  int m = (int)(off / N_DIM);
  int n = (int)(off % N_DIM);
  float sx = 0.f, sy = 0.f, sz = 0.f, sw = 0.f;
  for (int z = 0; z < ksplit; ++z){
    float4 p = *(const float4*)(part + (size_t)z * M_DIM * N_DIM + off);
    sx += p.x; sy += p.y; sz += p.z; sw += p.w;
  }
  float4 bv = *(const float4*)(bias + n);
  float g = gates[m];
  float4 o;
  o.x = g * (sx + bv.x); o.y = g * (sy + bv.y);
  o.z = g * (sz + bv.z); o.w = g * (sw + bv.w);
  *(float4*)(out + off) = o;
}

// K5b: finalize after atomic accumulation
__global__ __launch_bounds__(256)
void finalize_kernel(float* __restrict__ out, const float* __restrict__ gates,
                     const float* __restrict__ bias)
{
  int i4 = blockIdx.x * 256 + threadIdx.x;
  if (i4 >= M_DIM * N_DIM / 4) return;
  size_t off = (size_t)i4 * 4;
  int m = (int)(off / N_DIM);
  int n = (int)(off % N_DIM);
  float4 o = *(const float4*)(out + off);
  float4 bv = *(const float4*)(bias + n);
  float g = gates[m];
  o.x = g * (o.x + bv.x); o.y = g * (o.y + bv.y);
  o.z = g * (o.z + bv.z); o.w = g * (o.w + bv.w);
  *(float4*)(out + off) = o;
}

extern "C" void kernel_launch(void* const* d_in, const int* in_sizes, int n_in,
                              void* d_out, int out_size, void* d_ws, size_t ws_size,
                              hipStream_t stream)
{
  const float* input   = (const float*)d_in[0];
  const float* aw      = (const float*)d_in[2];
  const float* conv1_w = (const float*)d_in[3];
  const float* conv1_b = (const float*)d_in[4];
  const float* G3_w    = (const float*)d_in[5];
  const float* G3_b    = (const float*)d_in[6];
  const float* ffnn1_w = (const float*)d_in[7];
  const float* ffnn1_b = (const float*)d_in[8];
  float* out = (float*)d_out;

  float* wsf    = (float*)d_ws;
  float* w_mean = wsf;               // 16384 f
  float* pooled = wsf + 16384;       // 512 f
  float* gates  = wsf + 16896;       // 512 f
  float* b_mean = wsf + 17408;       // 64 f pad
  unsigned short* xbf = (unsigned short*)(wsf + 17472);        // 512*16384 bf16 = 16MB
  float* partial = wsf + 17472 + (size_t)M_DIM * K_DIM / 2;    // 8 * 512*2560 f

  const size_t need_det = ((size_t)17472 + (size_t)M_DIM * K_DIM / 2
                           + (size_t)KSPLIT * M_DIM * N_DIM) * 4;   // ~58.8MB

  prep_kernel<<<64, 256, 0, stream>>>(conv1_w, conv1_b, w_mean, b_mean);
  pooled_kernel<<<512, 256, 0, stream>>>(input, w_mean, b_mean, pooled, xbf);
  gates_kernel<<<1, 512, 0, stream>>>(pooled, ffnn1_w, ffnn1_b, aw, gates);

  const int n4 = M_DIM * N_DIM / 4;
  const int grid = (M_DIM / BM) * (N_DIM / BN) * KSPLIT;   // 4*16*8 = 512
  if (ws_size >= need_det){
    gemm_kernel<<<grid, 256, 0, stream>>>(xbf, G3_w, partial, 0);
    reduce_kernel<<<(n4 + 255) / 256, 256, 0, stream>>>(partial, gates, G3_b, out, KSPLIT);
  } else {
    hipMemsetAsync(d_out, 0, (size_t)out_size * sizeof(float), stream);
    gemm_kernel<<<grid, 256, 0, stream>>>(xbf, G3_w, out, 2);
    finalize_kernel<<<(n4 + 255) / 256, 256, 0, stream>>>(out, gates, G3_b);
  }
}